// Round 5
// baseline (413.318 us; speedup 1.0000x reference)
//
#include <hip/hip_runtime.h>

static inline int ceil_div(int a, int b){ return (a+b-1)/b; }

// ---------------- CSR build ----------------
__global__ __launch_bounds__(256) void k_hist(const int* __restrict__ dst, int E, int* __restrict__ cnt){
  int e = blockIdx.x*256 + threadIdx.x;
  if (e < E) atomicAdd(&cnt[dst[e]], 1);
}

__global__ __launch_bounds__(256) void k_scan_a(const int* __restrict__ cnt, int N, int* __restrict__ bsum){
  __shared__ int s[256];
  int t = threadIdx.x;
  int i0 = blockIdx.x*512 + 2*t;
  int a = (i0   < N) ? cnt[i0]   : 0;
  int b = (i0+1 < N) ? cnt[i0+1] : 0;
  s[t] = a + b;
  __syncthreads();
  for (int off=128; off>0; off>>=1){ if (t<off) s[t]+=s[t+off]; __syncthreads(); }
  if (t==0) bsum[blockIdx.x] = s[0];
}

// exclusive scan of bsum[0..nb), nb <= 1024: one block, 256 threads, 4 elems/thread
__global__ __launch_bounds__(256) void k_scan_b(int* __restrict__ bsum, int nb){
  __shared__ int s[256];
  int t = threadIdx.x;
  int v0=0,v1=0,v2=0,v3=0;
  int i0 = t*4;
  if (i0   < nb) v0 = bsum[i0];
  if (i0+1 < nb) v1 = bsum[i0+1];
  if (i0+2 < nb) v2 = bsum[i0+2];
  if (i0+3 < nb) v3 = bsum[i0+3];
  int tsum = v0+v1+v2+v3;
  s[t] = tsum;
  __syncthreads();
  for (int off=1; off<256; off<<=1){
    int v = (t>=off) ? s[t-off] : 0;
    __syncthreads();
    s[t] += v;
    __syncthreads();
  }
  int excl = s[t] - tsum;   // exclusive prefix of this thread's chunk
  if (i0   < nb) bsum[i0]   = excl;
  if (i0+1 < nb) bsum[i0+1] = excl + v0;
  if (i0+2 < nb) bsum[i0+2] = excl + v0 + v1;
  if (i0+3 < nb) bsum[i0+3] = excl + v0 + v1 + v2;
}

__global__ __launch_bounds__(256) void k_scan_c(const int* __restrict__ cnt, int N,
                                                const int* __restrict__ bsum, int* __restrict__ offs){
  __shared__ int s[256];
  int t = threadIdx.x;
  int i0 = blockIdx.x*512 + 2*t;
  int a = (i0   < N) ? cnt[i0]   : 0;
  int b = (i0+1 < N) ? cnt[i0+1] : 0;
  int tsum = a+b;
  s[t] = tsum;
  __syncthreads();
  for (int off=1; off<256; off<<=1){
    int v = (t>=off) ? s[t-off] : 0;
    __syncthreads();
    s[t] += v;
    __syncthreads();
  }
  int excl = s[t] - tsum + bsum[blockIdx.x];
  if (i0   < N) offs[i0]   = excl;
  if (i0+1 < N) offs[i0+1] = excl + a;
}

__global__ __launch_bounds__(256) void k_place(const int* __restrict__ src, const int* __restrict__ dst, int E,
                                               const int* __restrict__ offs, int* __restrict__ cursor,
                                               int* __restrict__ ss){
  int e = blockIdx.x*256 + threadIdx.x;
  if (e < E){
    int d = dst[e];
    int p = atomicAdd(&cursor[d], 1);
    ss[offs[d] + p] = src[e];
  }
}

// ---------------- Layer 1: aggregate (pull, one wave per node) ----------------
__global__ __launch_bounds__(256) void k_agg1(const float* __restrict__ feats,
    const int* __restrict__ ss, const int* __restrict__ offs, const int* __restrict__ cnt,
    float* __restrict__ aggout, int N){
  int w = (int)((blockIdx.x*256u + threadIdx.x) >> 6);
  int lane = threadIdx.x & 63;
  if (w >= N) return;
  int beg = __builtin_amdgcn_readfirstlane(offs[w]);
  int c   = __builtin_amdgcn_readfirstlane(cnt[w]);
  const float2* f2 = (const float2*)feats;
  float2 acc = f2[(size_t)w*64 + lane];   // self term
  int i = 0;
  for (; i+4 <= c; i += 4){               // 4 row-loads in flight (latency hiding)
    int s0 = ss[beg+i], s1 = ss[beg+i+1], s2 = ss[beg+i+2], s3 = ss[beg+i+3];
    float2 a = f2[(size_t)s0*64 + lane];
    float2 b = f2[(size_t)s1*64 + lane];
    float2 cc= f2[(size_t)s2*64 + lane];
    float2 d = f2[(size_t)s3*64 + lane];
    acc.x += (a.x + b.x) + (cc.x + d.x);
    acc.y += (a.y + b.y) + (cc.y + d.y);
  }
  for (; i < c; ++i){
    int s0 = ss[beg+i];
    float2 a = f2[(size_t)s0*64 + lane];
    acc.x += a.x; acc.y += a.y;
  }
  float inv = 1.0f / (float)(c + 1);
  float2 o; o.x = acc.x*inv; o.y = acc.y*inv;
  ((float2*)aggout)[(size_t)w*64 + lane] = o;
}

// ---------------- Layer 1: in-place GEMM + bias + relu ----------------
// h1[r,:] = relu(agg[r,:] @ W1 + b1), agg lives in h1 region (in-place per 64-row tile)
__global__ __launch_bounds__(256) void k_gemm1(float* __restrict__ h1,
    const float* __restrict__ W1, const float* __restrict__ b1, int N){
  __shared__ float sA[64*132];
  __shared__ float sW[32*128];
  int t = threadIdx.x;
  int r0 = blockIdx.x*64;
  for (int it=0; it<8; ++it){
    int flat = it*1024 + t*4;
    int r = flat>>7, d = flat&127;
    float4 v = make_float4(0.f,0.f,0.f,0.f);
    if (r0+r < N) v = *(const float4*)(h1 + (size_t)(r0+r)*128 + d);
    *(float4*)&sA[r*132 + d] = v;
  }
  int rg = t>>4, cg = t&15;          // rows {rg,rg+16,rg+32,rg+48}, cols {cg*4..+3, 64+cg*4..+3}
  float acc[4][8];
#pragma unroll
  for (int i=0;i<4;++i)
#pragma unroll
    for (int j=0;j<8;++j) acc[i][j]=0.f;

  for (int kc=0; kc<4; ++kc){
    __syncthreads();
#pragma unroll
    for (int it=0; it<4; ++it){
      int flat = it*1024 + t*4;
      *(float4*)&sW[flat] = *(const float4*)(W1 + kc*4096 + flat);
    }
    __syncthreads();
#pragma unroll 4
    for (int dd=0; dd<32; ++dd){
      int d = kc*32 + dd;
      float4 w0 = *(const float4*)&sW[dd*128 + cg*4];
      float4 w1 = *(const float4*)&sW[dd*128 + 64 + cg*4];
      float a0 = sA[(rg   )*132 + d];
      float a1 = sA[(rg+16)*132 + d];
      float a2 = sA[(rg+32)*132 + d];
      float a3 = sA[(rg+48)*132 + d];
      acc[0][0]+=a0*w0.x; acc[0][1]+=a0*w0.y; acc[0][2]+=a0*w0.z; acc[0][3]+=a0*w0.w;
      acc[0][4]+=a0*w1.x; acc[0][5]+=a0*w1.y; acc[0][6]+=a0*w1.z; acc[0][7]+=a0*w1.w;
      acc[1][0]+=a1*w0.x; acc[1][1]+=a1*w0.y; acc[1][2]+=a1*w0.z; acc[1][3]+=a1*w0.w;
      acc[1][4]+=a1*w1.x; acc[1][5]+=a1*w1.y; acc[1][6]+=a1*w1.z; acc[1][7]+=a1*w1.w;
      acc[2][0]+=a2*w0.x; acc[2][1]+=a2*w0.y; acc[2][2]+=a2*w0.z; acc[2][3]+=a2*w0.w;
      acc[2][4]+=a2*w1.x; acc[2][5]+=a2*w1.y; acc[2][6]+=a2*w1.z; acc[2][7]+=a2*w1.w;
      acc[3][0]+=a3*w0.x; acc[3][1]+=a3*w0.y; acc[3][2]+=a3*w0.z; acc[3][3]+=a3*w0.w;
      acc[3][4]+=a3*w1.x; acc[3][5]+=a3*w1.y; acc[3][6]+=a3*w1.z; acc[3][7]+=a3*w1.w;
    }
  }
  float4 bb0 = *(const float4*)(b1 + cg*4);
  float4 bb1 = *(const float4*)(b1 + 64 + cg*4);
#pragma unroll
  for (int i=0;i<4;++i){
    int r = r0 + rg + i*16;
    if (r < N){
      float4 o0, o1;
      o0.x = fmaxf(acc[i][0]+bb0.x, 0.f); o0.y = fmaxf(acc[i][1]+bb0.y, 0.f);
      o0.z = fmaxf(acc[i][2]+bb0.z, 0.f); o0.w = fmaxf(acc[i][3]+bb0.w, 0.f);
      o1.x = fmaxf(acc[i][4]+bb1.x, 0.f); o1.y = fmaxf(acc[i][5]+bb1.y, 0.f);
      o1.z = fmaxf(acc[i][6]+bb1.z, 0.f); o1.w = fmaxf(acc[i][7]+bb1.w, 0.f);
      *(float4*)(h1 + (size_t)r*128 + cg*4)      = o0;
      *(float4*)(h1 + (size_t)r*128 + 64 + cg*4) = o1;
    }
  }
}

// ---------------- Layer 2: transform first (t1 = h1 @ W2), then aggregate ----------------
__global__ __launch_bounds__(256) void k_gemm2(const float* __restrict__ h1,
    const float* __restrict__ W2, float* __restrict__ t1, int N){
  __shared__ float sA[64*132];
  __shared__ float sW[128*40];
  int t = threadIdx.x;
  int r0 = blockIdx.x*64;
  for (int it=0; it<8; ++it){
    int flat = it*1024 + t*4;
    int r = flat>>7, d = flat&127;
    float4 v = make_float4(0.f,0.f,0.f,0.f);
    if (r0+r < N) v = *(const float4*)(h1 + (size_t)(r0+r)*128 + d);
    *(float4*)&sA[r*132 + d] = v;
  }
#pragma unroll
  for (int it=0; it<5; ++it){
    int flat = it*1024 + t*4;
    *(float4*)&sW[flat] = *(const float4*)(W2 + flat);
  }
  __syncthreads();
  int rg = t>>3, cg = t&7;   // rows {rg, rg+32}, cols {cg + 8*jj, jj=0..4}
  float acc[2][5];
#pragma unroll
  for (int i=0;i<2;++i)
#pragma unroll
    for (int j=0;j<5;++j) acc[i][j]=0.f;
#pragma unroll 4
  for (int d=0; d<128; ++d){
    float a0 = sA[(rg   )*132 + d];
    float a1 = sA[(rg+32)*132 + d];
#pragma unroll
    for (int jj=0;jj<5;++jj){
      float wv = sW[d*40 + cg + 8*jj];
      acc[0][jj] += a0*wv;
      acc[1][jj] += a1*wv;
    }
  }
#pragma unroll
  for (int i=0;i<2;++i){
    int r = r0 + rg + i*32;
    if (r < N){
#pragma unroll
      for (int jj=0;jj<5;++jj) t1[(size_t)r*40 + cg + 8*jj] = acc[i][jj];
    }
  }
}

// h2[v,:] = (sum_neigh t1[s,:] + t1[v,:]) / (deg+1) + b2
__global__ __launch_bounds__(256) void k_agg2(const float* __restrict__ t1,
    const int* __restrict__ ss, const int* __restrict__ offs, const int* __restrict__ cnt,
    const float* __restrict__ b2, float* __restrict__ h2, int N){
  int w = (int)((blockIdx.x*256u + threadIdx.x) >> 6);
  int lane = threadIdx.x & 63;
  if (w >= N) return;
  int beg = __builtin_amdgcn_readfirstlane(offs[w]);
  int c   = __builtin_amdgcn_readfirstlane(cnt[w]);
  int l = (lane < 40) ? lane : 0;
  float acc = t1[(size_t)w*40 + l];
  int i = 0;
  for (; i+4 <= c; i += 4){
    int s0 = ss[beg+i], s1 = ss[beg+i+1], s2 = ss[beg+i+2], s3 = ss[beg+i+3];
    float a = t1[(size_t)s0*40 + l];
    float b = t1[(size_t)s1*40 + l];
    float cc= t1[(size_t)s2*40 + l];
    float d = t1[(size_t)s3*40 + l];
    acc += (a + b) + (cc + d);
  }
  for (; i < c; ++i) acc += t1[(size_t)ss[beg+i]*40 + l];
  float inv = 1.0f / (float)(c + 1);
  if (lane < 40) h2[(size_t)w*40 + lane] = acc*inv + b2[lane];
}

extern "C" void kernel_launch(void* const* d_in, const int* in_sizes, int n_in,
                              void* d_out, int out_size, void* d_ws, size_t ws_size,
                              hipStream_t stream){
  const float* feats = (const float*)d_in[0];
  const int*   src   = (const int*)d_in[1];
  const int*   dst   = (const int*)d_in[2];
  const float* W1    = (const float*)d_in[3];
  const float* b1    = (const float*)d_in[4];
  const float* W2    = (const float*)d_in[5];
  const float* b2    = (const float*)d_in[6];
  int N = in_sizes[0] / 128;
  int E = in_sizes[1];
  float* h1 = (float*)d_out;
  float* h2 = h1 + (size_t)N*128;

  // ws layout (tripwire: if ws_size is too small, bail cleanly instead of OOB-crashing the container)
  size_t need = 0;
  auto lay = [&](size_t bytes)->size_t{ size_t p = need; need += (bytes + 511) & ~(size_t)511; return p; };
  size_t o_cnt    = lay((size_t)N*4);
  size_t o_offs   = lay((size_t)N*4);
  size_t o_cursor = lay((size_t)N*4);
  size_t o_bsum   = lay(4096);
  size_t o_ss     = lay((size_t)E*4);
  size_t o_t1     = lay((size_t)N*40*4);
  if (need > ws_size) return;  // diagnostic: harness will report incorrect output, not a dead container

  char* wp = (char*)d_ws;
  int*   cnt    = (int*)(wp + o_cnt);
  int*   offs   = (int*)(wp + o_offs);
  int*   cursor = (int*)(wp + o_cursor);
  int*   bsum   = (int*)(wp + o_bsum);
  int*   ss     = (int*)(wp + o_ss);
  float* t1     = (float*)(wp + o_t1);

  hipMemsetAsync(cnt,    0, (size_t)N*4, stream);
  hipMemsetAsync(cursor, 0, (size_t)N*4, stream);

  int nb = ceil_div(N, 512);
  k_hist  <<<ceil_div(E,256), 256, 0, stream>>>(dst, E, cnt);
  k_scan_a<<<nb,              256, 0, stream>>>(cnt, N, bsum);
  k_scan_b<<<1,               256, 0, stream>>>(bsum, nb);
  k_scan_c<<<nb,              256, 0, stream>>>(cnt, N, bsum, offs);
  k_place <<<ceil_div(E,256), 256, 0, stream>>>(src, dst, E, offs, cursor, ss);

  k_agg1  <<<ceil_div(N,4),   256, 0, stream>>>(feats, ss, offs, cnt, h1, N);
  k_gemm1 <<<ceil_div(N,64),  256, 0, stream>>>(h1, W1, b1, N);
  k_gemm2 <<<ceil_div(N,64),  256, 0, stream>>>(h1, W2, t1, N);
  k_agg2  <<<ceil_div(N,4),   256, 0, stream>>>(t1, ss, offs, cnt, b2, h2, N);
}